// Round 10
// baseline (161.061 us; speedup 1.0000x reference)
//
#include <hip/hip_runtime.h>

// MoE router, fp32-accurate via bf16-split MFMA (verified absmax 9.8e-4).
// x = token_inputs * jitter; logits = x @ w + b; softmax E=64; top-2 mask.
// Tokens = 32768, H = 2048, E = 64.
//
// R10: kill the vmcnt(0) barrier drain (R9: __syncthreads drained a
// just-issued HBM load every k-step -> ~900cy exposed, VALUBusy 17% matches
// 150/(150+900)). T4 pattern: counted s_waitcnt vmcnt(12) + RAW s_barrier
// (no drain) -> 12 global_load_lds (3 k-steps ahead) stay in flight ACROSS
// barriers. Wait-own-then-barrier makes cross-wave staging correct.
// NBUF=4 x 16 KB = 64 KB/block, 2 blocks/CU; 96 KB outstanding/CU >> the
// ~8 KB Little's-law requirement for ~5 TB/s.

#define H   2048
#define E   64
#define NKS 64               // k-steps of 32

typedef __attribute__((ext_vector_type(8))) short bf16x8;
typedef __attribute__((ext_vector_type(4))) float f32x4;

#define GBL(p)  ((const __attribute__((address_space(1))) void*)(p))
#define LDSP(p) ((__attribute__((address_space(3))) void*)(p))

__device__ inline ushort f2bf_rne(float f) {
    union { float f; unsigned u; } c; c.f = f;
    const unsigned r = (c.u + 0x7FFFu + ((c.u >> 16) & 1u)) >> 16;
    return (ushort)r;
}
__device__ inline float bf2f(ushort h) {
    union { unsigned u; float f; } c; c.u = ((unsigned)h) << 16;
    return c.f;
}

// ---- pre-kernel: pack w into fragment-linear hi/lo bf16 (verified) ----
// frag-pair (ks,n) at bp + (ks*4+n)*1024 ushorts: hi [0,512), lo [512,1024).
// slot s of lane (g,c) holds w[ks*32 + g*8 + s][n*16 + c].
__global__ __launch_bounds__(256)
void wpack_kernel(const float* __restrict__ w, ushort* __restrict__ bp)
{
    const int t    = blockIdx.x * 256 + threadIdx.x;  // 0..16383
    const int lane = t & 63;
    const int n    = (t >> 6) & 3;
    const int ks   = t >> 8;                          // 0..63
    const int c    = lane & 15, g = lane >> 4;

    const float* src = w + (size_t)(ks * 32 + g * 8) * E + n * 16 + c;
    bf16x8 vh, vl;
#pragma unroll
    for (int s = 0; s < 8; ++s) {
        const float  v = src[(size_t)s * E];
        const ushort h = f2bf_rne(v);
        vh[s] = (short)h;
        vl[s] = (short)f2bf_rne(v - bf2f(h));
    }
    ushort* d = bp + ((size_t)(ks * 4 + n) * 2 * 64 + lane) * 8;
    *(bf16x8*)d         = vh;
    *(bf16x8*)(d + 512) = vl;
}

// ---- main kernel ----
__global__ __launch_bounds__(256, 2)
void router_kernel(const float* __restrict__ xg,
                   const float* __restrict__ jg,
                   const ushort* __restrict__ bp,
                   const float* __restrict__ bias,
                   float* __restrict__ out)
{
    // 4 buffers x 16 KB. Buffer b at smem + b*16384:
    //   xs [32 tok][32 k] f32 (4 KB), quad kq of row t stored at (kq+t)&7
    //   js same (4 KB)
    //   bs [8 frags][512] ushort (8 KB), frag = n*2+hl, lane-linear
    __shared__ __align__(16) unsigned char smem[65536];
#define XS(b) ((float (*)[32])(void*)(smem + (b) * 16384))
#define JS(b) ((float (*)[32])(void*)(smem + (b) * 16384 + 4096))
#define BS(b) ((ushort (*)[512])(void*)(smem + (b) * 16384 + 8192))

    const int tid  = threadIdx.x;
    const int wv   = tid >> 6;
    const int lane = tid & 63;
    const int ln   = lane & 15;        // MFMA col / A-row token
    const int g    = lane >> 4;        // k-group
    const int mh   = wv >> 1;          // token half
    const int nh   = wv & 1;           // expert half
    const size_t tokBase = (size_t)blockIdx.x * 32;

    // staging source coords: lane covers dest tok wv*8 + (lane>>3);
    // dest quad pos lane&7 holds source quad ((lane&7)-(lane>>3))&7
    const int srow = lane >> 3;
    const int sqd  = ((lane & 7) - srow) & 7;
    const float* xsb = xg + (tokBase + wv * 8 + srow) * (size_t)H + sqd * 4;
    const float* jsb = jg + (tokBase + wv * 8 + srow) * (size_t)H + sqd * 4;
    const ushort* bsb = bp + (size_t)wv * 1024 + (size_t)lane * 8;

    const int t = mh * 16 + ln;

    f32x4 acc0 = (f32x4){0.f, 0.f, 0.f, 0.f};
    f32x4 acc1 = (f32x4){0.f, 0.f, 0.f, 0.f};

#define STAGE(bb, c) do {                                                     \
        __builtin_amdgcn_global_load_lds(GBL(xsb + (size_t)(c) * 32),         \
                                         LDSP(&XS(bb)[wv * 8][0]), 16, 0, 0); \
        __builtin_amdgcn_global_load_lds(GBL(jsb + (size_t)(c) * 32),         \
                                         LDSP(&JS(bb)[wv * 8][0]), 16, 0, 0); \
        __builtin_amdgcn_global_load_lds(GBL(bsb + (size_t)(c) * 4096),       \
                                         LDSP(&BS(bb)[wv * 2][0]), 16, 0, 0); \
        __builtin_amdgcn_global_load_lds(GBL(bsb + (size_t)(c) * 4096 + 512), \
                                         LDSP(&BS(bb)[wv * 2 + 1][0]), 16, 0, 0); \
    } while (0)

#define COMPUTE(bb) do {                                                      \
        const int p0 = ((2 * g + t) & 7) << 2;                                \
        const int p1 = ((2 * g + 1 + t) & 7) << 2;                            \
        const float4 xq0 = *(const float4*)&XS(bb)[t][p0];                    \
        const float4 xq1 = *(const float4*)&XS(bb)[t][p1];                    \
        const float4 jq0 = *(const float4*)&JS(bb)[t][p0];                    \
        const float4 jq1 = *(const float4*)&JS(bb)[t][p1];                    \
        float pr[8];                                                          \
        pr[0] = xq0.x * jq0.x; pr[1] = xq0.y * jq0.y;                         \
        pr[2] = xq0.z * jq0.z; pr[3] = xq0.w * jq0.w;                         \
        pr[4] = xq1.x * jq1.x; pr[5] = xq1.y * jq1.y;                         \
        pr[6] = xq1.z * jq1.z; pr[7] = xq1.w * jq1.w;                         \
        bf16x8 ah, al;                                                        \
        _Pragma("unroll")                                                     \
        for (int i_ = 0; i_ < 8; ++i_) {                                      \
            const ushort h_ = f2bf_rne(pr[i_]);                               \
            ah[i_] = (short)h_;                                               \
            al[i_] = (short)f2bf_rne(pr[i_] - bf2f(h_));                      \
        }                                                                     \
        const bf16x8 BH0 = *(const bf16x8*)&BS(bb)[4 * nh + 0][lane * 8];     \
        const bf16x8 BL0 = *(const bf16x8*)&BS(bb)[4 * nh + 1][lane * 8];     \
        const bf16x8 BH1 = *(const bf16x8*)&BS(bb)[4 * nh + 2][lane * 8];     \
        const bf16x8 BL1 = *(const bf16x8*)&BS(bb)[4 * nh + 3][lane * 8];     \
        acc0 = __builtin_amdgcn_mfma_f32_16x16x32_bf16(ah, BH0, acc0, 0, 0, 0); \
        acc0 = __builtin_amdgcn_mfma_f32_16x16x32_bf16(al, BH0, acc0, 0, 0, 0); \
        acc0 = __builtin_amdgcn_mfma_f32_16x16x32_bf16(ah, BL0, acc0, 0, 0, 0); \
        acc1 = __builtin_amdgcn_mfma_f32_16x16x32_bf16(ah, BH1, acc1, 0, 0, 0); \
        acc1 = __builtin_amdgcn_mfma_f32_16x16x32_bf16(al, BH1, acc1, 0, 0, 0); \
        acc1 = __builtin_amdgcn_mfma_f32_16x16x32_bf16(ah, BL1, acc1, 0, 0, 0); \
    } while (0)

#define VMWAIT(N) do {                                            \
        asm volatile("s_waitcnt vmcnt(" #N ")" ::: "memory");     \
        __builtin_amdgcn_sched_barrier(0);                        \
    } while (0)

#define SBAR() do {                                               \
        __builtin_amdgcn_sched_barrier(0);                        \
        __builtin_amdgcn_s_barrier();                             \
        __builtin_amdgcn_sched_barrier(0);                        \
    } while (0)

    // substep: drain own step-c loads (keep 12 newer in flight), join,
    // compute, join (write-protect: nobody still reads buf bb), restage.
#define SUBSTEP(bb, c) do {                                       \
        VMWAIT(12); SBAR();                                       \
        COMPUTE(bb);                                              \
        SBAR();                                                   \
        STAGE(bb, (c) + 4);                                       \
    } while (0)

    // ---- prologue: fill all 4 buffers ----
    STAGE(0, 0); STAGE(1, 1); STAGE(2, 2); STAGE(3, 3);

    // ---- main loop: steps 0..59, staging 4..63 ----
#pragma unroll 1
    for (int i = 0; i < 15; ++i) {
        const int c = i * 4;
        SUBSTEP(0, c + 0);
        SUBSTEP(1, c + 1);
        SUBSTEP(2, c + 2);
        SUBSTEP(3, c + 3);
    }
    // ---- tail: steps 60..63, no staging, waits 12/8/4/0 ----
    VMWAIT(12); SBAR(); COMPUTE(0);
    VMWAIT(8);  SBAR(); COMPUTE(1);
    VMWAIT(4);  SBAR(); COMPUTE(2);
    VMWAIT(0);  SBAR(); COMPUTE(3);

    // ---- exchange logits via LDS overlay (rows padded to 68 words) ----
    float (*lgx)[68] = (float (*)[68])(void*)smem;
#pragma unroll
    for (int r = 0; r < 4; ++r) {
        lgx[mh * 16 + g * 4 + r][nh * 32 + ln]      = acc0[r];
        lgx[mh * 16 + g * 4 + r][nh * 32 + 16 + ln] = acc1[r];
    }
    __syncthreads();

    // ---- softmax + top-2: 8 threads per token (verified logic) ----
    const int t8 = tid >> 3;           // token 0..31
    const int q8 = tid & 7;            // expert octet
    float l[8];
    *(float4*)&l[0] = *(const float4*)&lgx[t8][q8 * 8];
    *(float4*)&l[4] = *(const float4*)&lgx[t8][q8 * 8 + 4];
    const float4 bb0 = *(const float4*)(bias + q8 * 8);
    const float4 bb1 = *(const float4*)(bias + q8 * 8 + 4);
    l[0] += bb0.x; l[1] += bb0.y; l[2] += bb0.z; l[3] += bb0.w;
    l[4] += bb1.x; l[5] += bb1.y; l[6] += bb1.z; l[7] += bb1.w;

    float p1 = l[0]; int i1 = q8 * 8;
    float p2 = -3.0e38f; int i2 = q8 * 8;
#pragma unroll
    for (int i = 1; i < 8; ++i) {
        const int e = q8 * 8 + i;
        if (l[i] > p1)      { p2 = p1; i2 = i1; p1 = l[i]; i1 = e; }
        else if (l[i] > p2) { p2 = l[i]; i2 = e; }
    }

#pragma unroll
    for (int m = 1; m <= 4; m <<= 1) {
        const float q1 = __shfl_xor(p1, m, 8);
        const int   k1 = __shfl_xor(i1, m, 8);
        const float q2 = __shfl_xor(p2, m, 8);
        const int   k2 = __shfl_xor(i2, m, 8);
        const bool  bw = (q1 > p1) || (q1 == p1 && k1 < i1);
        const float f1 = bw ? q1 : p1;  const int fi1 = bw ? k1 : i1;
        const float lo = bw ? p1 : q1;  const int loi = bw ? i1 : k1;
        const float sn = bw ? q2 : p2;  const int sni = bw ? k2 : i2;
        const bool  rw = (lo > sn) || (lo == sn && loi < sni);
        p2 = rw ? lo : sn;  i2 = rw ? loi : sni;
        p1 = f1;            i1 = fi1;
    }

    float d = 0.f;
#pragma unroll
    for (int i = 0; i < 8; ++i) d += __expf(l[i] - p1);
#pragma unroll
    for (int m = 1; m <= 4; m <<= 1) d += __shfl_xor(d, m, 8);

    const float inv = 1.f / d;                 // top-1 prob
    const float w2  = __expf(p2 - p1) * inv;   // top-2 prob

    float* op = out + (tokBase + t8) * (size_t)E + q8 * 8;
    float4 v0, v1;
    v0.x = (q8 * 8 + 0 == i1) ? inv : (q8 * 8 + 0 == i2) ? w2 : 0.f;
    v0.y = (q8 * 8 + 1 == i1) ? inv : (q8 * 8 + 1 == i2) ? w2 : 0.f;
    v0.z = (q8 * 8 + 2 == i1) ? inv : (q8 * 8 + 2 == i2) ? w2 : 0.f;
    v0.w = (q8 * 8 + 3 == i1) ? inv : (q8 * 8 + 3 == i2) ? w2 : 0.f;
    v1.x = (q8 * 8 + 4 == i1) ? inv : (q8 * 8 + 4 == i2) ? w2 : 0.f;
    v1.y = (q8 * 8 + 5 == i1) ? inv : (q8 * 8 + 5 == i2) ? w2 : 0.f;
    v1.z = (q8 * 8 + 6 == i1) ? inv : (q8 * 8 + 6 == i2) ? w2 : 0.f;
    v1.w = (q8 * 8 + 7 == i1) ? inv : (q8 * 8 + 7 == i2) ? w2 : 0.f;
    *(float4*)op       = v0;
    *(float4*)(op + 4) = v1;
}

extern "C" void kernel_launch(void* const* d_in, const int* in_sizes, int n_in,
                              void* d_out, int out_size, void* d_ws, size_t ws_size,
                              hipStream_t stream)
{
    const float* x   = (const float*)d_in[0];
    const float* jit = (const float*)d_in[1];
    const float* w   = (const float*)d_in[2];
    const float* b   = (const float*)d_in[3];
    float*       out = (float*)d_out;

    ushort* bpack = (ushort*)d_ws;   // 512 frag-pairs x 1 KB = 512 KB

    hipLaunchKernelGGL(wpack_kernel, dim3(64), dim3(256), 0, stream, w, bpack);

    const int n_tok = in_sizes[0] / H;   // 32768
    dim3 grid(n_tok / 32), block(256);
    hipLaunchKernelGGL(router_kernel, grid, block, 0, stream,
                       x, jit, bpack, b, out);
}

// Round 11
// 145.858 us; speedup vs baseline: 1.1042x; 1.1042x over previous
//
#include <hip/hip_runtime.h>

// MoE router, fp32-accurate via bf16-split MFMA (verified absmax 9.8e-4).
// x = token_inputs * jitter; logits = x @ w + b; softmax E=64; top-2 mask.
// Tokens = 32768, H = 2048, E = 64.
//
// R11: break the LDS-DMA alias drain. R9/R10 carved all buffers from ONE
// __shared__ arena -> LLVM's waitcnt pass (which tracks global_load_lds
// destinations and inserts vmcnt waits before any ds_read that MAY alias a
// pending DMA) saw one object with unknown offsets -> compiler-inserted
// vmcnt(0)-equivalent before every COMPUTE's first ds_read. Hand-written
// vmcnt(12) was dead letter; every substep exposed full HBM latency
// (VALUBusy 17% == issue/(issue+drain) in both rounds).
// Fix: 12 DISTINCT __shared__ variables (xs0..3, js0..3, bs0..3) so alias
// analysis can discriminate; ds_read(xs0) only waits on DMAs into xs0,
// which VMWAIT(12) + the 4-buffer rotation already completed.
// Structure otherwise identical to R10 (counted vmcnt + raw s_barrier).

#define H   2048
#define E   64
#define NKS 64               // k-steps of 32

typedef __attribute__((ext_vector_type(8))) short bf16x8;
typedef __attribute__((ext_vector_type(4))) float f32x4;

#define GBL(p)  ((const __attribute__((address_space(1))) void*)(p))
#define LDSP(p) ((__attribute__((address_space(3))) void*)(p))

__device__ inline ushort f2bf_rne(float f) {
    union { float f; unsigned u; } c; c.f = f;
    const unsigned r = (c.u + 0x7FFFu + ((c.u >> 16) & 1u)) >> 16;
    return (ushort)r;
}
__device__ inline float bf2f(ushort h) {
    union { unsigned u; float f; } c; c.u = ((unsigned)h) << 16;
    return c.f;
}

// ---- pre-kernel: pack w into fragment-linear hi/lo bf16 (verified) ----
// frag-pair (ks,n) at bp + (ks*4+n)*1024 ushorts: hi [0,512), lo [512,1024).
// slot s of lane (g,c) holds w[ks*32 + g*8 + s][n*16 + c].
__global__ __launch_bounds__(256)
void wpack_kernel(const float* __restrict__ w, ushort* __restrict__ bp)
{
    const int t    = blockIdx.x * 256 + threadIdx.x;  // 0..16383
    const int lane = t & 63;
    const int n    = (t >> 6) & 3;
    const int ks   = t >> 8;                          // 0..63
    const int c    = lane & 15, g = lane >> 4;

    const float* src = w + (size_t)(ks * 32 + g * 8) * E + n * 16 + c;
    bf16x8 vh, vl;
#pragma unroll
    for (int s = 0; s < 8; ++s) {
        const float  v = src[(size_t)s * E];
        const ushort h = f2bf_rne(v);
        vh[s] = (short)h;
        vl[s] = (short)f2bf_rne(v - bf2f(h));
    }
    ushort* d = bp + ((size_t)(ks * 4 + n) * 2 * 64 + lane) * 8;
    *(bf16x8*)d         = vh;
    *(bf16x8*)(d + 512) = vl;
}

// ---- main kernel ----
__global__ __launch_bounds__(256, 2)
void router_kernel(const float* __restrict__ xg,
                   const float* __restrict__ jg,
                   const ushort* __restrict__ bp,
                   const float* __restrict__ bias,
                   float* __restrict__ out)
{
    // DISTINCT objects per buffer so LLVM's LDS-DMA alias tracking can
    // discriminate (the whole point of R11):
    __shared__ __align__(16) float  xs0[32][32], xs1[32][32], xs2[32][32], xs3[32][32];
    __shared__ __align__(16) float  js0[32][32], js1[32][32], js2[32][32], js3[32][32];
    __shared__ __align__(16) ushort bs0[8][512], bs1[8][512], bs2[8][512], bs3[8][512];
    __shared__ __align__(16) float  lgx[32][68];   // epilogue logit exchange

    const int tid  = threadIdx.x;
    const int wv   = tid >> 6;
    const int lane = tid & 63;
    const int ln   = lane & 15;        // MFMA col / A-row token
    const int g    = lane >> 4;        // k-group
    const int mh   = wv >> 1;          // token half
    const int nh   = wv & 1;           // expert half
    const size_t tokBase = (size_t)blockIdx.x * 32;

    // staging source coords: lane covers dest tok wv*8 + (lane>>3);
    // dest quad pos lane&7 holds source quad ((lane&7)-(lane>>3))&7
    const int srow = lane >> 3;
    const int sqd  = ((lane & 7) - srow) & 7;
    const float* xsb = xg + (tokBase + wv * 8 + srow) * (size_t)H + sqd * 4;
    const float* jsb = jg + (tokBase + wv * 8 + srow) * (size_t)H + sqd * 4;
    const ushort* bsb = bp + (size_t)wv * 1024 + (size_t)lane * 8;

    const int t = mh * 16 + ln;

    f32x4 acc0 = (f32x4){0.f, 0.f, 0.f, 0.f};
    f32x4 acc1 = (f32x4){0.f, 0.f, 0.f, 0.f};

#define STAGE_N(bb, c) do {                                                   \
        __builtin_amdgcn_global_load_lds(GBL(xsb + (size_t)(c) * 32),         \
                                         LDSP(&xs##bb[wv * 8][0]), 16, 0, 0); \
        __builtin_amdgcn_global_load_lds(GBL(jsb + (size_t)(c) * 32),         \
                                         LDSP(&js##bb[wv * 8][0]), 16, 0, 0); \
        __builtin_amdgcn_global_load_lds(GBL(bsb + (size_t)(c) * 4096),       \
                                         LDSP(&bs##bb[wv * 2][0]), 16, 0, 0); \
        __builtin_amdgcn_global_load_lds(GBL(bsb + (size_t)(c) * 4096 + 512), \
                                         LDSP(&bs##bb[wv * 2 + 1][0]), 16, 0, 0); \
    } while (0)

#define COMPUTE_N(bb) do {                                                    \
        const int p0 = ((2 * g + t) & 7) << 2;                                \
        const int p1 = ((2 * g + 1 + t) & 7) << 2;                            \
        const float4 xq0 = *(const float4*)&xs##bb[t][p0];                    \
        const float4 xq1 = *(const float4*)&xs##bb[t][p1];                    \
        const float4 jq0 = *(const float4*)&js##bb[t][p0];                    \
        const float4 jq1 = *(const float4*)&js##bb[t][p1];                    \
        float pr[8];                                                          \
        pr[0] = xq0.x * jq0.x; pr[1] = xq0.y * jq0.y;                         \
        pr[2] = xq0.z * jq0.z; pr[3] = xq0.w * jq0.w;                         \
        pr[4] = xq1.x * jq1.x; pr[5] = xq1.y * jq1.y;                         \
        pr[6] = xq1.z * jq1.z; pr[7] = xq1.w * jq1.w;                         \
        bf16x8 ah, al;                                                        \
        _Pragma("unroll")                                                     \
        for (int i_ = 0; i_ < 8; ++i_) {                                      \
            const ushort h_ = f2bf_rne(pr[i_]);                               \
            ah[i_] = (short)h_;                                               \
            al[i_] = (short)f2bf_rne(pr[i_] - bf2f(h_));                      \
        }                                                                     \
        const bf16x8 BH0 = *(const bf16x8*)&bs##bb[4 * nh + 0][lane * 8];     \
        const bf16x8 BL0 = *(const bf16x8*)&bs##bb[4 * nh + 1][lane * 8];     \
        const bf16x8 BH1 = *(const bf16x8*)&bs##bb[4 * nh + 2][lane * 8];     \
        const bf16x8 BL1 = *(const bf16x8*)&bs##bb[4 * nh + 3][lane * 8];     \
        acc0 = __builtin_amdgcn_mfma_f32_16x16x32_bf16(ah, BH0, acc0, 0, 0, 0); \
        acc0 = __builtin_amdgcn_mfma_f32_16x16x32_bf16(al, BH0, acc0, 0, 0, 0); \
        acc0 = __builtin_amdgcn_mfma_f32_16x16x32_bf16(ah, BL0, acc0, 0, 0, 0); \
        acc1 = __builtin_amdgcn_mfma_f32_16x16x32_bf16(ah, BH1, acc1, 0, 0, 0); \
        acc1 = __builtin_amdgcn_mfma_f32_16x16x32_bf16(al, BH1, acc1, 0, 0, 0); \
        acc1 = __builtin_amdgcn_mfma_f32_16x16x32_bf16(ah, BL1, acc1, 0, 0, 0); \
    } while (0)

#define VMWAIT(N) do {                                            \
        asm volatile("s_waitcnt vmcnt(" #N ")" ::: "memory");     \
        __builtin_amdgcn_sched_barrier(0);                        \
    } while (0)

#define SBAR() do {                                               \
        __builtin_amdgcn_sched_barrier(0);                        \
        __builtin_amdgcn_s_barrier();                             \
        __builtin_amdgcn_sched_barrier(0);                        \
    } while (0)

    // substep: drain own step-c loads (12 newer stay in flight), join,
    // compute, join (write-protect), restage buffer bb with step c+4.
#define SUBSTEP_N(bb, c) do {                                     \
        VMWAIT(12); SBAR();                                       \
        COMPUTE_N(bb);                                            \
        SBAR();                                                   \
        STAGE_N(bb, (c) + 4);                                     \
    } while (0)

    // ---- prologue: fill all 4 buffers ----
    STAGE_N(0, 0); STAGE_N(1, 1); STAGE_N(2, 2); STAGE_N(3, 3);

    // ---- main loop: steps 0..59, staging 4..63 ----
#pragma unroll 1
    for (int i = 0; i < 15; ++i) {
        const int c = i * 4;
        SUBSTEP_N(0, c + 0);
        SUBSTEP_N(1, c + 1);
        SUBSTEP_N(2, c + 2);
        SUBSTEP_N(3, c + 3);
    }
    // ---- tail: steps 60..63, no staging, waits 12/8/4/0 ----
    VMWAIT(12); SBAR(); COMPUTE_N(0);
    VMWAIT(8);  SBAR(); COMPUTE_N(1);
    VMWAIT(4);  SBAR(); COMPUTE_N(2);
    VMWAIT(0);  SBAR(); COMPUTE_N(3);

    // ---- exchange logits (separate lgx array; rows padded to 68) ----
#pragma unroll
    for (int r = 0; r < 4; ++r) {
        lgx[mh * 16 + g * 4 + r][nh * 32 + ln]      = acc0[r];
        lgx[mh * 16 + g * 4 + r][nh * 32 + 16 + ln] = acc1[r];
    }
    __syncthreads();

    // ---- softmax + top-2: 8 threads per token (verified logic) ----
    const int t8 = tid >> 3;           // token 0..31
    const int q8 = tid & 7;            // expert octet
    float l[8];
    *(float4*)&l[0] = *(const float4*)&lgx[t8][q8 * 8];
    *(float4*)&l[4] = *(const float4*)&lgx[t8][q8 * 8 + 4];
    const float4 bb0 = *(const float4*)(bias + q8 * 8);
    const float4 bb1 = *(const float4*)(bias + q8 * 8 + 4);
    l[0] += bb0.x; l[1] += bb0.y; l[2] += bb0.z; l[3] += bb0.w;
    l[4] += bb1.x; l[5] += bb1.y; l[6] += bb1.z; l[7] += bb1.w;

    float p1 = l[0]; int i1 = q8 * 8;
    float p2 = -3.0e38f; int i2 = q8 * 8;
#pragma unroll
    for (int i = 1; i < 8; ++i) {
        const int e = q8 * 8 + i;
        if (l[i] > p1)      { p2 = p1; i2 = i1; p1 = l[i]; i1 = e; }
        else if (l[i] > p2) { p2 = l[i]; i2 = e; }
    }

#pragma unroll
    for (int m = 1; m <= 4; m <<= 1) {
        const float q1 = __shfl_xor(p1, m, 8);
        const int   k1 = __shfl_xor(i1, m, 8);
        const float q2 = __shfl_xor(p2, m, 8);
        const int   k2 = __shfl_xor(i2, m, 8);
        const bool  bw = (q1 > p1) || (q1 == p1 && k1 < i1);
        const float f1 = bw ? q1 : p1;  const int fi1 = bw ? k1 : i1;
        const float lo = bw ? p1 : q1;  const int loi = bw ? i1 : k1;
        const float sn = bw ? q2 : p2;  const int sni = bw ? k2 : i2;
        const bool  rw = (lo > sn) || (lo == sn && loi < sni);
        p2 = rw ? lo : sn;  i2 = rw ? loi : sni;
        p1 = f1;            i1 = fi1;
    }

    float d = 0.f;
#pragma unroll
    for (int i = 0; i < 8; ++i) d += __expf(l[i] - p1);
#pragma unroll
    for (int m = 1; m <= 4; m <<= 1) d += __shfl_xor(d, m, 8);

    const float inv = 1.f / d;                 // top-1 prob
    const float w2  = __expf(p2 - p1) * inv;   // top-2 prob

    float* op = out + (tokBase + t8) * (size_t)E + q8 * 8;
    float4 v0, v1;
    v0.x = (q8 * 8 + 0 == i1) ? inv : (q8 * 8 + 0 == i2) ? w2 : 0.f;
    v0.y = (q8 * 8 + 1 == i1) ? inv : (q8 * 8 + 1 == i2) ? w2 : 0.f;
    v0.z = (q8 * 8 + 2 == i1) ? inv : (q8 * 8 + 2 == i2) ? w2 : 0.f;
    v0.w = (q8 * 8 + 3 == i1) ? inv : (q8 * 8 + 3 == i2) ? w2 : 0.f;
    v1.x = (q8 * 8 + 4 == i1) ? inv : (q8 * 8 + 4 == i2) ? w2 : 0.f;
    v1.y = (q8 * 8 + 5 == i1) ? inv : (q8 * 8 + 5 == i2) ? w2 : 0.f;
    v1.z = (q8 * 8 + 6 == i1) ? inv : (q8 * 8 + 6 == i2) ? w2 : 0.f;
    v1.w = (q8 * 8 + 7 == i1) ? inv : (q8 * 8 + 7 == i2) ? w2 : 0.f;
    *(float4*)op       = v0;
    *(float4*)(op + 4) = v1;
}

extern "C" void kernel_launch(void* const* d_in, const int* in_sizes, int n_in,
                              void* d_out, int out_size, void* d_ws, size_t ws_size,
                              hipStream_t stream)
{
    const float* x   = (const float*)d_in[0];
    const float* jit = (const float*)d_in[1];
    const float* w   = (const float*)d_in[2];
    const float* b   = (const float*)d_in[3];
    float*       out = (float*)d_out;

    ushort* bpack = (ushort*)d_ws;   // 512 frag-pairs x 1 KB = 512 KB

    hipLaunchKernelGGL(wpack_kernel, dim3(64), dim3(256), 0, stream, w, bpack);

    const int n_tok = in_sizes[0] / H;   // 32768
    dim3 grid(n_tok / 32), block(256);
    hipLaunchKernelGGL(router_kernel, grid, block, 0, stream,
                       x, jit, bpack, b, out);
}